// Round 2
// baseline (85.206 us; speedup 1.0000x reference)
//
#include <hip/hip_runtime.h>
#include <math.h>

#define NB 4096
#define NIN 128
#define NH 256
#define ND 32
#define NC 8
#define NK 256
#define NHS 16

// output offsets (in floats), concatenated in reference return order
#define OFF_KCHART 0
#define OFF_KCODE  4096
#define OFF_ZN     8192
#define OFF_ZTEX   (OFF_ZN + 4096*32)        // 139264
#define OFF_ROUTER (OFF_ZTEX + 4096*32)      // 270336 (float4-aligned)
#define OFF_ZGEO   (OFF_ROUTER + 4096*8)     // 303104
#define OFF_LOSS   (OFF_ZGEO + 4096*32)      // 434176
#define OFF_IND    (OFF_LOSS + 1)            // 434177 (odd -> scalar access only)
#define OFF_ZNALL  (OFF_IND + 4096*8)        // 466945 (odd -> scalar access only)
#define OFF_CBAR   (OFF_ZNALL + 4096*8*32)   // 1515521 (odd -> scalar)
#define OFF_VLOC   (OFF_CBAR + 4096*32)      // 1646593 (odd -> scalar)

__device__ __forceinline__ float gelu_exact(float x) {
    return x * (erff(x / 1.41421356237309504f) + 1.0f) * 0.5f;
}

// ---------------------------------------------------------------------------
// GEMM: out = gelu(A[M][K] @ W[K][256] + b). 64x64 tile, 256 thr, 4x4 micro,
// BK=32, register-prefetch double buffering of global loads.
// ---------------------------------------------------------------------------
template<int K>
__global__ __launch_bounds__(256)
void gemm_bias_gelu(const float* __restrict__ A, const float* __restrict__ W,
                    const float* __restrict__ bias, float* __restrict__ out) {
    const int N = 256;
    __shared__ float sA[32][68];   // [k][row]
    __shared__ float sB[32][68];   // [k][col]
    const int t  = threadIdx.x;
    const int n0 = blockIdx.x * 64;
    const int r0 = blockIdx.y * 64;
    const int ty = t >> 4, tx = t & 15;
    const int ar = t >> 3, ak = t & 7;    // A: 2 float4/thread (rows ar, ar+32)
    const int bk = t >> 4, bc = t & 15;   // B: 2 float4/thread (k-rows bk, bk+16)

    float4 bias4 = *(const float4*)(bias + n0 + tx * 4);
    float4 pa0, pa1, pb0, pb1;

    // prefetch tile 0
    pa0 = *(const float4*)(A + (r0 + ar) * K + ak * 4);
    pa1 = *(const float4*)(A + (r0 + ar + 32) * K + ak * 4);
    pb0 = *(const float4*)(W + bk * N + n0 + bc * 4);
    pb1 = *(const float4*)(W + (bk + 16) * N + n0 + bc * 4);

    float acc[4][4];
    #pragma unroll
    for (int i = 0; i < 4; i++)
        #pragma unroll
        for (int j = 0; j < 4; j++) acc[i][j] = 0.f;

    for (int kk = 0; kk < K; kk += 32) {
        // regs -> LDS
        sA[ak*4+0][ar] = pa0.x; sA[ak*4+1][ar] = pa0.y;
        sA[ak*4+2][ar] = pa0.z; sA[ak*4+3][ar] = pa0.w;
        sA[ak*4+0][ar+32] = pa1.x; sA[ak*4+1][ar+32] = pa1.y;
        sA[ak*4+2][ar+32] = pa1.z; sA[ak*4+3][ar+32] = pa1.w;
        *(float4*)(&sB[bk][bc*4])      = pb0;
        *(float4*)(&sB[bk+16][bc*4])   = pb1;
        __syncthreads();
        // prefetch next tile while computing this one
        if (kk + 32 < K) {
            pa0 = *(const float4*)(A + (r0 + ar) * K + kk + 32 + ak * 4);
            pa1 = *(const float4*)(A + (r0 + ar + 32) * K + kk + 32 + ak * 4);
            pb0 = *(const float4*)(W + (kk + 32 + bk) * N + n0 + bc * 4);
            pb1 = *(const float4*)(W + (kk + 32 + bk + 16) * N + n0 + bc * 4);
        }
        #pragma unroll
        for (int k = 0; k < 32; k++) {
            float4 av = *(const float4*)(&sA[k][ty * 4]);
            float4 bv = *(const float4*)(&sB[k][tx * 4]);
            float aa[4] = {av.x, av.y, av.z, av.w};
            float bb[4] = {bv.x, bv.y, bv.z, bv.w};
            #pragma unroll
            for (int i = 0; i < 4; i++)
                #pragma unroll
                for (int j = 0; j < 4; j++)
                    acc[i][j] = fmaf(aa[i], bb[j], acc[i][j]);
        }
        __syncthreads();
    }
    float bb4[4] = {bias4.x, bias4.y, bias4.z, bias4.w};
    #pragma unroll
    for (int i = 0; i < 4; i++) {
        int row = r0 + ty * 4 + i;
        float4 o;
        float* op = (float*)&o;
        #pragma unroll
        for (int j = 0; j < 4; j++) op[j] = gelu_exact(acc[i][j] + bb4[j]);
        *(float4*)(out + row * N + n0 + tx * 4) = o;
    }
}

// ---------------------------------------------------------------------------
// v = feats@Wv + bv ; softmax router ; K_chart ; c_bar ; v_local
// 16 rows/block, 256 threads (16 per row, cols cp and cp+16), grid 256
// Wv staged TRANSPOSED [col][k] with pad for b128 reads.
// ---------------------------------------------------------------------------
__global__ __launch_bounds__(256)
void router_kernel(const float* __restrict__ feats, const float* __restrict__ Wv,
                   const float* __restrict__ bv, const float* __restrict__ centers,
                   float* __restrict__ out, float* __restrict__ vloc_ws) {
    __shared__ float sWvT[ND][260];    // [col][k], stride 260 (1040B = 65*16 ok)
    __shared__ float sCent[NC * ND];
    __shared__ float sV[16][ND + 1];
    __shared__ float sRout[16][NC];
    const int t = threadIdx.x;
    {
        #pragma unroll
        for (int q = 0; q < 8; q++) {
            int id = t + q * 256;            // 2048 float4 of Wv (256x32)
            int k = id >> 3, c4 = (id & 7) * 4;
            float4 w = ((const float4*)Wv)[id];
            sWvT[c4 + 0][k] = w.x;
            sWvT[c4 + 1][k] = w.y;
            sWvT[c4 + 2][k] = w.z;
            sWvT[c4 + 3][k] = w.w;
        }
        if (t < 64) ((float4*)sCent)[t] = ((const float4*)centers)[t];
    }
    __syncthreads();
    const int r = t >> 4, cp = t & 15;
    const int row = blockIdx.x * 16 + r;
    float a0 = bv[cp], a1 = bv[cp + 16];
    const float4* f4 = (const float4*)(feats + row * NH);
    for (int k4 = 0; k4 < NH / 4; k4++) {
        float4 f = f4[k4];
        float4 w0 = *(const float4*)(&sWvT[cp][k4 * 4]);
        float4 w1 = *(const float4*)(&sWvT[cp + 16][k4 * 4]);
        a0 = fmaf(f.x, w0.x, a0); a1 = fmaf(f.x, w1.x, a1);
        a0 = fmaf(f.y, w0.y, a0); a1 = fmaf(f.y, w1.y, a1);
        a0 = fmaf(f.z, w0.z, a0); a1 = fmaf(f.z, w1.z, a1);
        a0 = fmaf(f.w, w0.w, a0); a1 = fmaf(f.w, w1.w, a1);
    }
    sV[r][cp] = a0; sV[r][cp + 16] = a1;
    __syncthreads();
    if (t < 16) {
        const int rr = t, grow = blockIdx.x * 16 + rr;
        float sc[NC];
        float m = -3.4e38f; int kmax = 0;
        #pragma unroll
        for (int c = 0; c < NC; c++) {
            float acc = 0.f;
            #pragma unroll
            for (int k = 0; k < ND; k++) acc = fmaf(sV[rr][k], sCent[c * ND + k], acc);
            acc = acc / 5.65685424949238f;
            sc[c] = acc;
            if (acc > m) { m = acc; kmax = c; }
        }
        float s = 0.f;
        #pragma unroll
        for (int c = 0; c < NC; c++) { float e = expf(sc[c] - m); sc[c] = e; s += e; }
        float inv = 1.f / s;
        #pragma unroll
        for (int c = 0; c < NC; c++) {
            float rv = sc[c] * inv;
            sRout[rr][c] = rv;
            out[OFF_ROUTER + grow * NC + c] = rv;
        }
        out[OFF_KCHART + grow] = (float)kmax;
    }
    __syncthreads();
    #pragma unroll
    for (int j = 0; j < 2; j++) {
        int col = cp + j * 16;
        float cb = 0.f;
        #pragma unroll
        for (int c = 0; c < NC; c++) cb = fmaf(sRout[r][c], sCent[c * ND + col], cb);
        float vl = sV[r][col] - cb;
        out[OFF_CBAR + row * ND + col] = cb;
        out[OFF_VLOC + row * ND + col] = vl;
        vloc_ws[row * ND + col] = vl;
    }
}

// ---------------------------------------------------------------------------
// Fused VQ: per 16-row block, loop over 8 charts: stage codebook in LDS,
// argmin (dot form), zn MLP (s1 via shuffles), blend accumulation, loss.
// Then finalize z_n/z_tex/z_geo/K_code. grid 256, 256 threads.
// thread t = (r = t>>4 row, i = t&15 lane-in-row)
// ---------------------------------------------------------------------------
__global__ __launch_bounds__(256)
void vq_fused(const float* __restrict__ codebook, const float* __restrict__ vloc_ws,
              const float* __restrict__ Ws1, const float* __restrict__ bs1,
              const float* __restrict__ Ws2, const float* __restrict__ bs2,
              float* __restrict__ out, float* __restrict__ loss_partial) {
    __shared__ float sCB[NK][36];     // padded; stride 144B = 9*16 (f4-aligned)
    __shared__ float sEn2[NK];
    __shared__ float sV[16][ND + 1];
    __shared__ float sRout[16][NC];
    __shared__ int   sIdx[16][NC];
    __shared__ float sWs1[ND][17];
    __shared__ float sWs2[NHS][33];
    __shared__ float sbs2v[ND];
    __shared__ float sRed[16];
    const int t = threadIdx.x;
    const int r = t >> 4, i = t & 15;
    const int row0 = blockIdx.x * 16, row = row0 + r;

    // --- one-time staging ---
    if (t < 128) {               // Ws1 (32x16) = 128 f4
        float4 w = ((const float4*)Ws1)[t];
        int k = t >> 2, o = (t & 3) * 4;
        sWs1[k][o] = w.x; sWs1[k][o+1] = w.y; sWs1[k][o+2] = w.z; sWs1[k][o+3] = w.w;
    } else {                     // Ws2 (16x32) = 128 f4
        int u = t - 128;
        float4 w = ((const float4*)Ws2)[u];
        int k = u >> 3, o = (u & 7) * 4;
        sWs2[k][o] = w.x; sWs2[k][o+1] = w.y; sWs2[k][o+2] = w.z; sWs2[k][o+3] = w.w;
    }
    if (t < ND) sbs2v[t] = bs2[t];
    if (t < 128) {               // v_local 16x32 = 128 f4
        int rr = t >> 3, q = t & 7;
        float4 a = ((const float4*)(vloc_ws + (row0 + rr) * ND))[q];
        sV[rr][q*4+0] = a.x; sV[rr][q*4+1] = a.y; sV[rr][q*4+2] = a.z; sV[rr][q*4+3] = a.w;
    } else if (t < 160) {        // router 16x8 = 32 f4
        int u = t - 128; int rr = u >> 1, h = u & 1;
        float4 a = *(const float4*)(out + OFF_ROUTER + (row0 + rr) * NC + h * 4);
        sRout[rr][h*4+0] = a.x; sRout[rr][h*4+1] = a.y;
        sRout[rr][h*4+2] = a.z; sRout[rr][h*4+3] = a.w;
    }
    __syncthreads();

    float vl[ND];
    #pragma unroll
    for (int k = 0; k < ND; k++) vl[k] = sV[r][k];
    float vn2 = 0.f;
    #pragma unroll
    for (int k = 0; k < ND; k++) vn2 = fmaf(vl[k], vl[k], vn2);
    const float pnorm = fmaxf(sqrtf(vn2), 1e-6f);
    const float pscale = fminf(0.99f / pnorm, 1.0f);
    const float b1r = bs1[i];
    const float bo0 = sbs2v[2*i], bo1 = sbs2v[2*i+1];

    float znb0 = 0.f, znb1 = 0.f, zqb0 = 0.f, zqb1 = 0.f, loss_acc = 0.f;

    for (int c = 0; c < NC; c++) {
        __syncthreads();   // protect sCB/sEn2 from previous iteration's readers
        // stage codebook[c] (256x32)
        {
            const float4* src = (const float4*)(codebook + c * NK * ND);
            #pragma unroll
            for (int q = 0; q < 8; q++) {
                int id = t + q * 256;
                int code = id >> 3, kq = (id & 7) * 4;
                *(float4*)(&sCB[code][kq]) = src[id];
            }
        }
        __syncthreads();
        // per-code squared norms
        {
            float s = 0.f;
            #pragma unroll
            for (int q = 0; q < 8; q++) {
                float4 e = *(const float4*)(&sCB[t][q*4]);
                s = fmaf(e.x, e.x, s); s = fmaf(e.y, e.y, s);
                s = fmaf(e.z, e.z, s); s = fmaf(e.w, e.w, s);
            }
            sEn2[t] = s;
        }
        __syncthreads();
        // argmin via dot form; codes j*16+i (adjacent lanes -> adjacent codes)
        float best = 3.4e38f; int bidx = 0;
        for (int j = 0; j < 16; j++) {
            const int code = j * 16 + i;
            float acc = 0.f;
            #pragma unroll
            for (int q = 0; q < 8; q++) {
                float4 e = *(const float4*)(&sCB[code][q*4]);
                acc = fmaf(vl[q*4+0], e.x, acc);
                acc = fmaf(vl[q*4+1], e.y, acc);
                acc = fmaf(vl[q*4+2], e.z, acc);
                acc = fmaf(vl[q*4+3], e.w, acc);
            }
            float d = sEn2[code] - 2.f * acc;
            if (d < best || (d == best && code < bidx)) { best = d; bidx = code; }
        }
        #pragma unroll
        for (int m = 1; m < 16; m <<= 1) {
            float ob = __shfl_xor(best, m, 16);
            int   oi = __shfl_xor(bidx, m, 16);
            if (ob < best || (ob == best && oi < bidx)) { best = ob; bidx = oi; }
        }
        const int sel = bidx;
        const float rc = sRout[r][c];
        if (i == 0) {
            out[OFF_IND + row * NC + c] = (float)sel;
            sIdx[r][c] = sel;
        }
        // zn MLP layer 1: this thread computes s1[i]
        float acc1 = b1r;
        #pragma unroll
        for (int k = 0; k < ND; k++) {
            float dlt = vl[k] - sCB[sel][k];
            acc1 = fmaf(dlt, sWs1[k][i], acc1);
        }
        float h = gelu_exact(acc1);
        // layer 2: cols 2i, 2i+1; s1 shared via width-16 shuffles
        float a0 = bo0, a1 = bo1;
        #pragma unroll
        for (int k = 0; k < NHS; k++) {
            float s1k = __shfl(h, k, 16);
            a0 = fmaf(s1k, sWs2[k][2*i],   a0);
            a1 = fmaf(s1k, sWs2[k][2*i+1], a1);
        }
        out[OFF_ZNALL + (row * NC + c) * ND + 2*i]     = a0;
        out[OFF_ZNALL + (row * NC + c) * ND + 2*i + 1] = a1;
        znb0 = fmaf(a0, rc, znb0);
        znb1 = fmaf(a1, rc, znb1);
        const float e0 = sCB[sel][2*i], e1 = sCB[sel][2*i+1];
        zqb0 = fmaf(e0, rc, zqb0);
        zqb1 = fmaf(e1, rc, zqb1);
        // loss partials: dims 2i, 2i+1
        float sq = 0.f, xn = 0.f, yn = 0.f;
        {
            float yp0 = sV[r][2*i] * pscale, yp1 = sV[r][2*i+1] * pscale;
            float d0 = e0 - yp0, d1 = e1 - yp1;
            sq = fmaf(d0, d0, fmaf(d1, d1, 0.f));
            xn = fmaf(e0, e0, fmaf(e1, e1, 0.f));
            yn = fmaf(yp0, yp0, fmaf(yp1, yp1, 0.f));
        }
        #pragma unroll
        for (int m = 1; m < 16; m <<= 1) {
            sq += __shfl_xor(sq, m, 16);
            xn += __shfl_xor(xn, m, 16);
            yn += __shfl_xor(yn, m, 16);
        }
        if (i == 0) {
            float denom = fmaxf((1.f - xn) * (1.f - yn), 1e-6f);
            float arg = fmaxf(1.f + 2.f * sq / denom, 1.f + 1e-6f);
            float dd = acoshf(arg);
            loss_acc += dd * dd * rc;
        }
    }

    // --- finalize: cols 2i, 2i+1 ---
    {
        const float v0 = sV[r][2*i], v1 = sV[r][2*i+1];
        const float cb0 = out[OFF_CBAR + row * ND + 2*i];
        const float cb1 = out[OFF_CBAR + row * ND + 2*i + 1];
        out[OFF_ZN   + row * ND + 2*i]     = znb0;
        out[OFF_ZN   + row * ND + 2*i + 1] = znb1;
        out[OFF_ZTEX + row * ND + 2*i]     = v0 - zqb0 - znb0;
        out[OFF_ZTEX + row * ND + 2*i + 1] = v1 - zqb1 - znb1;
        out[OFF_ZGEO + row * ND + 2*i]     = cb0 + zqb0 + znb0;
        out[OFF_ZGEO + row * ND + 2*i + 1] = cb1 + zqb1 + znb1;
        if (i == 0) {
            int kc = (int)out[OFF_KCHART + row];
            out[OFF_KCODE + row] = (float)sIdx[r][kc];
            sRed[r] = loss_acc;
        }
    }
    __syncthreads();
    if (t == 0) {
        float s = 0.f;
        #pragma unroll
        for (int rr = 0; rr < 16; rr++) s += sRed[rr];
        loss_partial[blockIdx.x] = s;
    }
}

__global__ __launch_bounds__(256)
void loss_reduce(const float* __restrict__ partials, float* __restrict__ out) {
    int t = threadIdx.x;
    float v = partials[t];
    #pragma unroll
    for (int off = 32; off > 0; off >>= 1) v += __shfl_down(v, off, 64);
    __shared__ float sTmp[4];
    if ((t & 63) == 0) sTmp[t >> 6] = v;
    __syncthreads();
    if (t == 0) out[OFF_LOSS] = 1.25f * (sTmp[0] + sTmp[1] + sTmp[2] + sTmp[3]) / 4096.f;
}

extern "C" void kernel_launch(void* const* d_in, const int* in_sizes, int n_in,
                              void* d_out, int out_size, void* d_ws, size_t ws_size,
                              hipStream_t stream) {
    const float* x        = (const float*)d_in[0];
    const float* W1       = (const float*)d_in[1];
    const float* b1       = (const float*)d_in[2];
    const float* W2       = (const float*)d_in[3];
    const float* b2       = (const float*)d_in[4];
    const float* Wv       = (const float*)d_in[5];
    const float* bv       = (const float*)d_in[6];
    const float* centers  = (const float*)d_in[7];
    const float* codebook = (const float*)d_in[8];
    const float* Ws1      = (const float*)d_in[9];
    const float* bs1      = (const float*)d_in[10];
    const float* Ws2      = (const float*)d_in[11];
    const float* bs2      = (const float*)d_in[12];
    float* out = (float*)d_out;
    float* ws  = (float*)d_ws;

    float* h1       = ws;                                // 4096*256
    float* feats    = ws + 4096 * 256;                   // 4096*256
    float* vloc     = ws + 2 * 4096 * 256;               // 4096*32
    float* partials = ws + 2 * 4096 * 256 + 4096 * 32;   // 256

    gemm_bias_gelu<128><<<dim3(4, 64), dim3(256), 0, stream>>>(x, W1, b1, h1);
    gemm_bias_gelu<256><<<dim3(4, 64), dim3(256), 0, stream>>>(h1, W2, b2, feats);
    router_kernel<<<dim3(256), dim3(256), 0, stream>>>(feats, Wv, bv, centers, out, vloc);
    vq_fused<<<dim3(256), dim3(256), 0, stream>>>(codebook, vloc, Ws1, bs1, Ws2, bs2, out, partials);
    loss_reduce<<<dim3(1), dim3(256), 0, stream>>>(partials, out);
}

// Round 3
// 68.596 us; speedup vs baseline: 1.2421x; 1.2421x over previous
//
#include <hip/hip_runtime.h>
#include <math.h>

#define NB 4096
#define NIN 128
#define NH 256
#define ND 32
#define NC 8
#define NK 256
#define NHS 16

// output offsets (in floats), concatenated in reference return order
#define OFF_KCHART 0
#define OFF_KCODE  4096
#define OFF_ZN     8192
#define OFF_ZTEX   (OFF_ZN + 4096*32)        // 139264
#define OFF_ROUTER (OFF_ZTEX + 4096*32)      // 270336 (float4-aligned)
#define OFF_ZGEO   (OFF_ROUTER + 4096*8)     // 303104
#define OFF_LOSS   (OFF_ZGEO + 4096*32)      // 434176
#define OFF_IND    (OFF_LOSS + 1)            // 434177 (odd -> scalar access only)
#define OFF_ZNALL  (OFF_IND + 4096*8)        // 466945 (odd -> scalar access only)
#define OFF_CBAR   (OFF_ZNALL + 4096*8*32)   // 1515521 (odd -> scalar)
#define OFF_VLOC   (OFF_CBAR + 4096*32)      // 1646593 (odd -> scalar)

__device__ __forceinline__ float gelu_exact(float x) {
    return x * (erff(x / 1.41421356237309504f) + 1.0f) * 0.5f;
}

// ---------------------------------------------------------------------------
// GEMM: out = gelu(A[M][K] @ W[K][256] + b). 64x64 tile, 256 thr, 4x4 micro,
// BK=32, register-prefetch double buffering of global loads.
// ---------------------------------------------------------------------------
template<int K>
__global__ __launch_bounds__(256)
void gemm_bias_gelu(const float* __restrict__ A, const float* __restrict__ W,
                    const float* __restrict__ bias, float* __restrict__ out) {
    const int N = 256;
    __shared__ float sA[32][68];   // [k][row]
    __shared__ float sB[32][68];   // [k][col]
    const int t  = threadIdx.x;
    const int n0 = blockIdx.x * 64;
    const int r0 = blockIdx.y * 64;
    const int ty = t >> 4, tx = t & 15;
    const int ar = t >> 3, ak = t & 7;    // A: 2 float4/thread (rows ar, ar+32)
    const int bk = t >> 4, bc = t & 15;   // B: 2 float4/thread (k-rows bk, bk+16)

    float4 bias4 = *(const float4*)(bias + n0 + tx * 4);
    float4 pa0, pa1, pb0, pb1;

    pa0 = *(const float4*)(A + (r0 + ar) * K + ak * 4);
    pa1 = *(const float4*)(A + (r0 + ar + 32) * K + ak * 4);
    pb0 = *(const float4*)(W + bk * N + n0 + bc * 4);
    pb1 = *(const float4*)(W + (bk + 16) * N + n0 + bc * 4);

    float acc[4][4];
    #pragma unroll
    for (int i = 0; i < 4; i++)
        #pragma unroll
        for (int j = 0; j < 4; j++) acc[i][j] = 0.f;

    for (int kk = 0; kk < K; kk += 32) {
        sA[ak*4+0][ar] = pa0.x; sA[ak*4+1][ar] = pa0.y;
        sA[ak*4+2][ar] = pa0.z; sA[ak*4+3][ar] = pa0.w;
        sA[ak*4+0][ar+32] = pa1.x; sA[ak*4+1][ar+32] = pa1.y;
        sA[ak*4+2][ar+32] = pa1.z; sA[ak*4+3][ar+32] = pa1.w;
        *(float4*)(&sB[bk][bc*4])      = pb0;
        *(float4*)(&sB[bk+16][bc*4])   = pb1;
        __syncthreads();
        if (kk + 32 < K) {
            pa0 = *(const float4*)(A + (r0 + ar) * K + kk + 32 + ak * 4);
            pa1 = *(const float4*)(A + (r0 + ar + 32) * K + kk + 32 + ak * 4);
            pb0 = *(const float4*)(W + (kk + 32 + bk) * N + n0 + bc * 4);
            pb1 = *(const float4*)(W + (kk + 32 + bk + 16) * N + n0 + bc * 4);
        }
        #pragma unroll
        for (int k = 0; k < 32; k++) {
            float4 av = *(const float4*)(&sA[k][ty * 4]);
            float4 bv = *(const float4*)(&sB[k][tx * 4]);
            float aa[4] = {av.x, av.y, av.z, av.w};
            float bb[4] = {bv.x, bv.y, bv.z, bv.w};
            #pragma unroll
            for (int i = 0; i < 4; i++)
                #pragma unroll
                for (int j = 0; j < 4; j++)
                    acc[i][j] = fmaf(aa[i], bb[j], acc[i][j]);
        }
        __syncthreads();
    }
    float bb4[4] = {bias4.x, bias4.y, bias4.z, bias4.w};
    #pragma unroll
    for (int i = 0; i < 4; i++) {
        int row = r0 + ty * 4 + i;
        float4 o;
        float* op = (float*)&o;
        #pragma unroll
        for (int j = 0; j < 4; j++) op[j] = gelu_exact(acc[i][j] + bb4[j]);
        *(float4*)(out + row * N + n0 + tx * 4) = o;
    }
}

// ---------------------------------------------------------------------------
// v = feats@Wv + bv ; softmax router ; K_chart ; c_bar ; v_local
// ---------------------------------------------------------------------------
__global__ __launch_bounds__(256)
void router_kernel(const float* __restrict__ feats, const float* __restrict__ Wv,
                   const float* __restrict__ bv, const float* __restrict__ centers,
                   float* __restrict__ out, float* __restrict__ vloc_ws) {
    __shared__ float sWvT[ND][260];
    __shared__ float sCent[NC * ND];
    __shared__ float sV[16][ND + 1];
    __shared__ float sRout[16][NC];
    const int t = threadIdx.x;
    {
        #pragma unroll
        for (int q = 0; q < 8; q++) {
            int id = t + q * 256;
            int k = id >> 3, c4 = (id & 7) * 4;
            float4 w = ((const float4*)Wv)[id];
            sWvT[c4 + 0][k] = w.x;
            sWvT[c4 + 1][k] = w.y;
            sWvT[c4 + 2][k] = w.z;
            sWvT[c4 + 3][k] = w.w;
        }
        if (t < 64) ((float4*)sCent)[t] = ((const float4*)centers)[t];
    }
    __syncthreads();
    const int r = t >> 4, cp = t & 15;
    const int row = blockIdx.x * 16 + r;
    float a0 = bv[cp], a1 = bv[cp + 16];
    const float4* f4 = (const float4*)(feats + row * NH);
    for (int k4 = 0; k4 < NH / 4; k4++) {
        float4 f = f4[k4];
        float4 w0 = *(const float4*)(&sWvT[cp][k4 * 4]);
        float4 w1 = *(const float4*)(&sWvT[cp + 16][k4 * 4]);
        a0 = fmaf(f.x, w0.x, a0); a1 = fmaf(f.x, w1.x, a1);
        a0 = fmaf(f.y, w0.y, a0); a1 = fmaf(f.y, w1.y, a1);
        a0 = fmaf(f.z, w0.z, a0); a1 = fmaf(f.z, w1.z, a1);
        a0 = fmaf(f.w, w0.w, a0); a1 = fmaf(f.w, w1.w, a1);
    }
    sV[r][cp] = a0; sV[r][cp + 16] = a1;
    __syncthreads();
    if (t < 16) {
        const int rr = t, grow = blockIdx.x * 16 + rr;
        float sc[NC];
        float m = -3.4e38f; int kmax = 0;
        #pragma unroll
        for (int c = 0; c < NC; c++) {
            float acc = 0.f;
            #pragma unroll
            for (int k = 0; k < ND; k++) acc = fmaf(sV[rr][k], sCent[c * ND + k], acc);
            acc = acc / 5.65685424949238f;
            sc[c] = acc;
            if (acc > m) { m = acc; kmax = c; }
        }
        float s = 0.f;
        #pragma unroll
        for (int c = 0; c < NC; c++) { float e = expf(sc[c] - m); sc[c] = e; s += e; }
        float inv = 1.f / s;
        #pragma unroll
        for (int c = 0; c < NC; c++) {
            float rv = sc[c] * inv;
            sRout[rr][c] = rv;
            out[OFF_ROUTER + grow * NC + c] = rv;
        }
        out[OFF_KCHART + grow] = (float)kmax;
    }
    __syncthreads();
    #pragma unroll
    for (int j = 0; j < 2; j++) {
        int col = cp + j * 16;
        float cb = 0.f;
        #pragma unroll
        for (int c = 0; c < NC; c++) cb = fmaf(sRout[r][c], sCent[c * ND + col], cb);
        float vl = sV[r][col] - cb;
        out[OFF_CBAR + row * ND + col] = cb;
        out[OFF_VLOC + row * ND + col] = vl;
        vloc_ws[row * ND + col] = vl;
    }
}

// ---------------------------------------------------------------------------
// vq_chart: block = 64 rows x 1 chart. grid 512 (rowtile, chart).
// Phase B argmin: thread (r=t&31, g=t>>5): rows r, r+32 in regs; codes
//   g*32..g*32+31 streamed from LDS (2-address broadcast reads).
// Phase C: zn MLP (16 lanes/row, 4 passes) + hyperbolic loss partial.
// ---------------------------------------------------------------------------
__global__ __launch_bounds__(256)
void vq_chart(const float* __restrict__ codebook, const float* __restrict__ vloc_ws,
              const float* __restrict__ Ws1, const float* __restrict__ bs1,
              const float* __restrict__ Ws2, const float* __restrict__ bs2,
              float* __restrict__ out, float* __restrict__ loss_partial) {
    __shared__ float sCB[NK][36];       // 36.9 KB, 16B-aligned rows
    __shared__ float sV[64][36];        // 9.2 KB
    __shared__ float sBest[8][64];
    __shared__ int   sBidx[8][64];
    __shared__ int   sSel[64];
    __shared__ float sRoutv[64];
    __shared__ float sPscale[64];
    __shared__ float sLossArr[64];
    __shared__ float sWs1[ND][17];
    __shared__ float sWs2[NHS][33];
    __shared__ float sbs1[NHS], sbs2v[ND];
    const int t = threadIdx.x;
    const int c = blockIdx.x & 7;
    const int row0 = (blockIdx.x >> 3) * 64;

    // ---- staging ----
    {
        const float4* src = (const float4*)(codebook + c * NK * ND);
        #pragma unroll
        for (int q = 0; q < 8; q++) {
            int id = t + q * 256;
            int code = id >> 3, kq = (id & 7) * 4;
            *(float4*)(&sCB[code][kq]) = src[id];
        }
        #pragma unroll
        for (int q = 0; q < 2; q++) {
            int id = t + q * 256;           // 512 float4 of v_local (64x32)
            int rr = id >> 3, kq = (id & 7) * 4;
            *(float4*)(&sV[rr][kq]) = ((const float4*)(vloc_ws + row0 * ND))[id];
        }
    }
    if (t < 128) {
        float4 w = ((const float4*)Ws1)[t];
        int k = t >> 2, o = (t & 3) * 4;
        sWs1[k][o] = w.x; sWs1[k][o+1] = w.y; sWs1[k][o+2] = w.z; sWs1[k][o+3] = w.w;
    } else {
        int u = t - 128;
        float4 w = ((const float4*)Ws2)[u];
        int k = u >> 3, o = (u & 7) * 4;
        sWs2[k][o] = w.x; sWs2[k][o+1] = w.y; sWs2[k][o+2] = w.z; sWs2[k][o+3] = w.w;
    }
    if (t < NHS) sbs1[t] = bs1[t];
    else if (t < NHS + ND) sbs2v[t - NHS] = bs2[t - NHS];
    if (t < 64) sRoutv[t] = out[OFF_ROUTER + (row0 + t) * NC + c];
    __syncthreads();

    // ---- phase B: argmin ----
    const int r = t & 31, g = t >> 5;
    float vl0[ND], vl1[ND];
    #pragma unroll
    for (int q = 0; q < 8; q++) {
        float4 a = *(const float4*)(&sV[r][q * 4]);
        vl0[q*4] = a.x; vl0[q*4+1] = a.y; vl0[q*4+2] = a.z; vl0[q*4+3] = a.w;
        float4 b = *(const float4*)(&sV[r + 32][q * 4]);
        vl1[q*4] = b.x; vl1[q*4+1] = b.y; vl1[q*4+2] = b.z; vl1[q*4+3] = b.w;
    }
    float best0 = 3.4e38f, best1 = 3.4e38f;
    int bi0 = 0, bi1 = 0;
    for (int j = 0; j < 32; j++) {
        const int code = g * 32 + j;
        float dot0 = 0.f, dot1 = 0.f, en2 = 0.f;
        #pragma unroll
        for (int q = 0; q < 8; q++) {
            float4 e = *(const float4*)(&sCB[code][q * 4]);
            en2  = fmaf(e.x, e.x, en2);
            dot0 = fmaf(vl0[q*4+0], e.x, dot0); dot1 = fmaf(vl1[q*4+0], e.x, dot1);
            en2  = fmaf(e.y, e.y, en2);
            dot0 = fmaf(vl0[q*4+1], e.y, dot0); dot1 = fmaf(vl1[q*4+1], e.y, dot1);
            en2  = fmaf(e.z, e.z, en2);
            dot0 = fmaf(vl0[q*4+2], e.z, dot0); dot1 = fmaf(vl1[q*4+2], e.z, dot1);
            en2  = fmaf(e.w, e.w, en2);
            dot0 = fmaf(vl0[q*4+3], e.w, dot0); dot1 = fmaf(vl1[q*4+3], e.w, dot1);
        }
        float d0 = en2 - 2.f * dot0;
        float d1 = en2 - 2.f * dot1;
        if (d0 < best0) { best0 = d0; bi0 = code; }
        if (d1 < best1) { best1 = d1; bi1 = code; }
    }
    sBest[g][r] = best0;      sBidx[g][r] = bi0;
    sBest[g][r + 32] = best1; sBidx[g][r + 32] = bi1;
    // pscale while argmin results settle
    __syncthreads();
    if (t < 64) {
        float bb = sBest[0][t]; int ii = sBidx[0][t];
        #pragma unroll
        for (int gg = 1; gg < 8; gg++) {
            float v = sBest[gg][t];
            if (v < bb) { bb = v; ii = sBidx[gg][t]; }   // ascending groups = ascending idx
        }
        sSel[t] = ii;
        out[OFF_IND + (row0 + t) * NC + c] = (float)ii;
        float vn2 = 0.f;
        #pragma unroll
        for (int k = 0; k < ND; k++) { float v = sV[t][k]; vn2 = fmaf(v, v, vn2); }
        float norm = fmaxf(sqrtf(vn2), 1e-6f);
        sPscale[t] = fminf(0.99f / norm, 1.0f);
    }
    __syncthreads();

    // ---- phase C: zn MLP + loss, 4 passes of 16 rows ----
    const int i = t & 15, r16 = t >> 4;
    const float b1r = sbs1[i];
    const float bo0 = sbs2v[2*i], bo1 = sbs2v[2*i+1];
    #pragma unroll
    for (int pass = 0; pass < 4; pass++) {
        const int lrow = pass * 16 + r16;
        const int grow = row0 + lrow;
        const int sel = sSel[lrow];
        const float rc = sRoutv[lrow];
        const float ps = sPscale[lrow];
        // layer 1: s1[i]
        float acc1 = b1r;
        #pragma unroll
        for (int k = 0; k < ND; k++) {
            float dlt = sV[lrow][k] - sCB[sel][k];
            acc1 = fmaf(dlt, sWs1[k][i], acc1);
        }
        float h = gelu_exact(acc1);
        // layer 2: cols 2i, 2i+1
        float a0 = bo0, a1 = bo1;
        #pragma unroll
        for (int k = 0; k < NHS; k++) {
            float s1k = __shfl(h, k, 16);
            a0 = fmaf(s1k, sWs2[k][2*i],   a0);
            a1 = fmaf(s1k, sWs2[k][2*i+1], a1);
        }
        out[OFF_ZNALL + (grow * NC + c) * ND + 2*i]     = a0;
        out[OFF_ZNALL + (grow * NC + c) * ND + 2*i + 1] = a1;
        // loss partials (dims 2i, 2i+1)
        const float e0 = sCB[sel][2*i], e1 = sCB[sel][2*i+1];
        float yp0 = sV[lrow][2*i] * ps, yp1 = sV[lrow][2*i+1] * ps;
        float d0 = e0 - yp0, d1 = e1 - yp1;
        float sq = fmaf(d0, d0, d1 * d1);
        float xn = fmaf(e0, e0, e1 * e1);
        float yn = fmaf(yp0, yp0, yp1 * yp1);
        #pragma unroll
        for (int m = 1; m < 16; m <<= 1) {
            sq += __shfl_xor(sq, m, 16);
            xn += __shfl_xor(xn, m, 16);
            yn += __shfl_xor(yn, m, 16);
        }
        if (i == 0) {
            float denom = fmaxf((1.f - xn) * (1.f - yn), 1e-6f);
            float arg = fmaxf(1.f + 2.f * sq / denom, 1.f + 1e-6f);
            float dd = acoshf(arg);
            sLossArr[lrow] = dd * dd * rc;
        }
    }
    __syncthreads();
    if (t < 64) {
        float v = sLossArr[t];
        #pragma unroll
        for (int off = 32; off > 0; off >>= 1) v += __shfl_down(v, off, 64);
        if (t == 0) loss_partial[blockIdx.x] = v;
    }
}

// ---------------------------------------------------------------------------
// finalize: blends + z_n/z_tex/z_geo + K_code. thread = (row, col-pair).
// grid 256 x 256 thr: 16 threads per row.
// ---------------------------------------------------------------------------
__global__ __launch_bounds__(256)
void finalize_kernel(const float* __restrict__ codebook, const float* __restrict__ vloc_ws,
                     float* __restrict__ out) {
    const int gid = blockIdx.x * 256 + threadIdx.x;
    const int row = gid >> 4;
    const int cp = gid & 15;
    float rout[NC]; int ind[NC];
    #pragma unroll
    for (int cc = 0; cc < NC; cc++) {
        rout[cc] = out[OFF_ROUTER + row * NC + cc];
        ind[cc]  = (int)out[OFF_IND + row * NC + cc];
    }
    float zn0 = 0.f, zn1 = 0.f, zq0 = 0.f, zq1 = 0.f;
    #pragma unroll
    for (int cc = 0; cc < NC; cc++) {
        const float rcc = rout[cc];
        zn0 = fmaf(out[OFF_ZNALL + (row * NC + cc) * ND + 2*cp],     rcc, zn0);
        zn1 = fmaf(out[OFF_ZNALL + (row * NC + cc) * ND + 2*cp + 1], rcc, zn1);
        const float* e = codebook + (cc * NK + ind[cc]) * ND + 2*cp;
        zq0 = fmaf(e[0], rcc, zq0);
        zq1 = fmaf(e[1], rcc, zq1);
    }
    const float v0 = vloc_ws[row * ND + 2*cp], v1 = vloc_ws[row * ND + 2*cp + 1];
    const float cb0 = out[OFF_CBAR + row * ND + 2*cp];
    const float cb1 = out[OFF_CBAR + row * ND + 2*cp + 1];
    out[OFF_ZN   + row * ND + 2*cp]     = zn0;
    out[OFF_ZN   + row * ND + 2*cp + 1] = zn1;
    out[OFF_ZTEX + row * ND + 2*cp]     = v0 - zq0 - zn0;
    out[OFF_ZTEX + row * ND + 2*cp + 1] = v1 - zq1 - zn1;
    out[OFF_ZGEO + row * ND + 2*cp]     = cb0 + zq0 + zn0;
    out[OFF_ZGEO + row * ND + 2*cp + 1] = cb1 + zq1 + zn1;
    if (cp == 0) {
        int kc = (int)out[OFF_KCHART + row];
        out[OFF_KCODE + row] = out[OFF_IND + row * NC + kc];
    }
}

__global__ __launch_bounds__(256)
void loss_reduce(const float* __restrict__ partials, float* __restrict__ out) {
    int t = threadIdx.x;
    float v = partials[t] + partials[t + 256];
    #pragma unroll
    for (int off = 32; off > 0; off >>= 1) v += __shfl_down(v, off, 64);
    __shared__ float sTmp[4];
    if ((t & 63) == 0) sTmp[t >> 6] = v;
    __syncthreads();
    if (t == 0) out[OFF_LOSS] = 1.25f * (sTmp[0] + sTmp[1] + sTmp[2] + sTmp[3]) / 4096.f;
}

extern "C" void kernel_launch(void* const* d_in, const int* in_sizes, int n_in,
                              void* d_out, int out_size, void* d_ws, size_t ws_size,
                              hipStream_t stream) {
    const float* x        = (const float*)d_in[0];
    const float* W1       = (const float*)d_in[1];
    const float* b1       = (const float*)d_in[2];
    const float* W2       = (const float*)d_in[3];
    const float* b2       = (const float*)d_in[4];
    const float* Wv       = (const float*)d_in[5];
    const float* bv       = (const float*)d_in[6];
    const float* centers  = (const float*)d_in[7];
    const float* codebook = (const float*)d_in[8];
    const float* Ws1      = (const float*)d_in[9];
    const float* bs1      = (const float*)d_in[10];
    const float* Ws2      = (const float*)d_in[11];
    const float* bs2      = (const float*)d_in[12];
    float* out = (float*)d_out;
    float* ws  = (float*)d_ws;

    float* h1       = ws;                                // 4096*256
    float* feats    = ws + 4096 * 256;                   // 4096*256
    float* vloc     = ws + 2 * 4096 * 256;               // 4096*32
    float* partials = ws + 2 * 4096 * 256 + 4096 * 32;   // 512

    gemm_bias_gelu<128><<<dim3(4, 64), dim3(256), 0, stream>>>(x, W1, b1, h1);
    gemm_bias_gelu<256><<<dim3(4, 64), dim3(256), 0, stream>>>(h1, W2, b2, feats);
    router_kernel<<<dim3(256), dim3(256), 0, stream>>>(feats, Wv, bv, centers, out, vloc);
    vq_chart<<<dim3(512), dim3(256), 0, stream>>>(codebook, vloc, Ws1, bs1, Ws2, bs2, out, partials);
    finalize_kernel<<<dim3(256), dim3(256), 0, stream>>>(codebook, vloc, out);
    loss_reduce<<<dim3(1), dim3(256), 0, stream>>>(partials, out);
}